// Round 1
// baseline (60.527 us; speedup 1.0000x reference)
//
#include <hip/hip_runtime.h>

// 256 independent MLPs: x[16384,2] -> h=gelu(x@W0[c].T + b0[c]) (32) -> out[b,c,2]
// VALU-bound (134M gelu evals). Lane=batch row; channel wave-uniform -> scalar
// weight loads. LDS transpose for coalesced output writes.

#define NCH   256
#define HID   32
#define BATCH 16384
#define TPB   256   // threads per block = batch rows per block
#define CPB   16    // channels per block

__global__ __launch_bounds__(TPB, 4) void fused_mlp_kernel(
    const float* __restrict__ x,    // [BATCH,2]
    const float* __restrict__ W0,   // [NCH,HID,2]
    const float* __restrict__ b0,   // [NCH,HID]
    const float* __restrict__ W1,   // [NCH,2,HID]
    const float* __restrict__ b1,   // [NCH,2]
    float* __restrict__ out)        // [BATCH,NCH,2]
{
    // gelu(x) ~= x * sigmoid(1.5957691*(x + 0.044715 x^3)); fold log2(e) so we
    // can use v_exp_f32 (exp2) directly.
    constexpr float K0 = (float)(1.5957691216057308 * 1.4426950408889634);
    constexpr float K1 = (float)(1.5957691216057308 * 0.044715 * 1.4426950408889634);

    __shared__ float tile[TPB][CPB * 2 + 1];   // [b_local][c_local*2+o], pad->conflict-free

    const int tid  = threadIdx.x;
    const int nbb  = BATCH / TPB;              // 64 batch blocks
    const int bblk = blockIdx.x % nbb;
    const int cblk = blockIdx.x / nbb;
    const int b    = bblk * TPB + tid;
    const int c0   = cblk * CPB;

    const float2 xv = *reinterpret_cast<const float2*>(x + (size_t)b * 2);
    const float x0 = xv.x, x1 = xv.y;

    for (int cl = 0; cl < CPB; ++cl) {
        const int c = c0 + cl;                 // wave-uniform -> scalar loads below
        const float* __restrict__ w0 = W0 + (size_t)c * (HID * 2);
        const float* __restrict__ bb = b0 + (size_t)c * HID;
        const float* __restrict__ w1 = W1 + (size_t)c * (2 * HID);

        float acc0 = b1[c * 2 + 0];
        float acc1 = b1[c * 2 + 1];

        #pragma unroll
        for (int h = 0; h < HID; ++h) {
            float pre = fmaf(x0, w0[2 * h], fmaf(x1, w0[2 * h + 1], bb[h]));
            // tanh-approx gelu via sigmoid + exp2
            float y = pre * pre;
            float t = fmaf(K1, y, K0);
            float z = pre * t;                     // z = log2(e)*2a*(pre + c*pre^3)
            float e = __builtin_amdgcn_exp2f(-z);  // v_exp_f32
            float g = pre * __builtin_amdgcn_rcpf(1.0f + e);
            acc0 = fmaf(g, w1[h], acc0);
            acc1 = fmaf(g, w1[HID + h], acc1);
        }

        tile[tid][cl * 2 + 0] = acc0;
        tile[tid][cl * 2 + 1] = acc1;
    }

    __syncthreads();

    // Coalesced writeback: block's tile is [TPB][CPB*2] -> out[bblk*TPB + bl][c0 + j/2][j&1]
    float* __restrict__ obase = out + (size_t)bblk * TPB * (NCH * 2) + (size_t)c0 * 2;
    #pragma unroll
    for (int i = 0; i < CPB * 2; ++i) {
        int flat = i * TPB + tid;
        int bl   = flat >> 5;        // / (CPB*2)
        int j    = flat & (CPB * 2 - 1);
        obase[(size_t)bl * (NCH * 2) + j] = tile[bl][j];
    }
}

extern "C" void kernel_launch(void* const* d_in, const int* in_sizes, int n_in,
                              void* d_out, int out_size, void* d_ws, size_t ws_size,
                              hipStream_t stream) {
    const float* x  = (const float*)d_in[0];
    const float* W0 = (const float*)d_in[1];
    const float* b0 = (const float*)d_in[2];
    const float* W1 = (const float*)d_in[3];
    const float* b1 = (const float*)d_in[4];
    float* out = (float*)d_out;

    dim3 grid((BATCH / TPB) * (NCH / CPB));
    dim3 block(TPB);
    fused_mlp_kernel<<<grid, block, 0, stream>>>(x, W0, b0, W1, b1, out);
}

// Round 2
// 53.574 us; speedup vs baseline: 1.1298x; 1.1298x over previous
//
#include <hip/hip_runtime.h>

// 256 independent MLPs (2->32->2, tanh-approx GELU), 16384 rows.
// VALU/trans-bound. Round 2: (a) CPB 16->8 for 32 waves/CU occupancy,
// (b) h-pair packing as float2 -> v_pk_fma_f32, (c) shared v_rcp per h-pair
// (r_a = rcp(wa*wb)*wb) to cut transcendental issue cycles.

typedef float f32x2 __attribute__((ext_vector_type(2)));

#define NCH   256
#define HID   32
#define BATCH 16384
#define TPB   256   // threads per block = batch rows per block
#define CPB   8     // channels per block

__global__ __launch_bounds__(TPB, 8) void fused_mlp_kernel(
    const float* __restrict__ x,    // [BATCH,2]
    const float* __restrict__ W0,   // [NCH,HID,2]
    const float* __restrict__ b0,   // [NCH,HID]
    const float* __restrict__ W1,   // [NCH,2,HID]
    const float* __restrict__ b1,   // [NCH,2]
    float* __restrict__ out)        // [BATCH,NCH,2]
{
    // gelu(x) ~= x * sigmoid(1.5957691*(x + 0.044715 x^3)), log2(e) folded,
    // sign folded so exp2 arg is computed directly (no negate).
    constexpr float NK0 = -(float)(1.5957691216057308 * 1.4426950408889634);
    constexpr float NK1 = -(float)(1.5957691216057308 * 0.044715 * 1.4426950408889634);

    __shared__ f32x2 tile[TPB][CPB + 1];   // (out0,out1) per (row, channel); pad row

    const int tid  = threadIdx.x;
    const int nbb  = BATCH / TPB;          // 64 batch blocks
    const int bblk = blockIdx.x % nbb;
    const int cblk = blockIdx.x / nbb;
    const int b    = bblk * TPB + tid;
    const int c0   = cblk * CPB;

    const float2 xv = *reinterpret_cast<const float2*>(x + (size_t)b * 2);
    const f32x2 x0v = {xv.x, xv.x};
    const f32x2 x1v = {xv.y, xv.y};

    for (int cl = 0; cl < CPB; ++cl) {
        const int c = c0 + cl;             // wave-uniform -> scalar weight loads
        const float* __restrict__ w0 = W0 + (size_t)c * (HID * 2);
        const float* __restrict__ bb = b0 + (size_t)c * HID;
        const float* __restrict__ w1 = W1 + (size_t)c * (2 * HID);

        f32x2 acc0 = {b1[c * 2 + 0], 0.0f};   // lane-pair accumulators over h-pairs
        f32x2 acc1 = {b1[c * 2 + 1], 0.0f};

        #pragma unroll
        for (int hp = 0; hp < HID / 2; ++hp) {
            // h = 2*hp, 2*hp+1 packed in .x/.y
            const f32x2 w0a = {w0[4 * hp + 0], w0[4 * hp + 2]};   // i=0
            const f32x2 w0b = {w0[4 * hp + 1], w0[4 * hp + 3]};   // i=1
            const f32x2 bbp = {bb[2 * hp + 0], bb[2 * hp + 1]};

            f32x2 pre = x0v * w0a + (x1v * w0b + bbp);            // 2x v_pk_fma_f32
            f32x2 p2  = pre * pre;
            f32x2 tn  = f32x2{NK1, NK1} * p2 + f32x2{NK0, NK0};
            f32x2 zn  = pre * tn;                                  // = -z (exp2 arg)

            f32x2 e;
            e.x = __builtin_amdgcn_exp2f(zn.x);
            e.y = __builtin_amdgcn_exp2f(zn.y);

            f32x2 w = e + f32x2{1.0f, 1.0f};
            float R = __builtin_amdgcn_rcpf(w.x * w.y);            // one rcp / pair
            f32x2 r = {R * w.y, R * w.x};                          // 1/w.x, 1/w.y
            f32x2 g = pre * r;

            const f32x2 w1a = {w1[2 * hp + 0], w1[2 * hp + 1]};          // o=0
            const f32x2 w1b = {w1[HID + 2 * hp + 0], w1[HID + 2 * hp + 1]}; // o=1
            acc0 = acc0 + g * w1a;                                 // v_pk_fma_f32
            acc1 = acc1 + g * w1b;
        }

        tile[tid][cl] = f32x2{acc0.x + acc0.y, acc1.x + acc1.y};
    }

    __syncthreads();

    // Coalesced writeback: out as f32x2 array [BATCH][NCH]
    f32x2* __restrict__ out2 = reinterpret_cast<f32x2*>(out);
    const size_t obase = (size_t)bblk * TPB * NCH + c0;
    #pragma unroll
    for (int i = 0; i < CPB; ++i) {
        int flat = i * TPB + tid;
        int bl   = flat >> 3;      // / CPB
        int jp   = flat & (CPB - 1);
        out2[obase + (size_t)bl * NCH + jp] = tile[bl][jp];
    }
}

extern "C" void kernel_launch(void* const* d_in, const int* in_sizes, int n_in,
                              void* d_out, int out_size, void* d_ws, size_t ws_size,
                              hipStream_t stream) {
    const float* x  = (const float*)d_in[0];
    const float* W0 = (const float*)d_in[1];
    const float* b0 = (const float*)d_in[2];
    const float* W1 = (const float*)d_in[3];
    const float* b1 = (const float*)d_in[4];
    float* out = (float*)d_out;

    dim3 grid((BATCH / TPB) * (NCH / CPB));
    dim3 block(TPB);
    fused_mlp_kernel<<<grid, block, 0, stream>>>(x, W0, b0, W1, b1, out);
}